// Round 6
// baseline (131.052 us; speedup 1.0000x reference)
//
#include <hip/hip_runtime.h>

#define N 4096
#define D 256
#define MARGIN 0.3f
#define BIG 10000.0f

typedef _Float16 f16x8 __attribute__((ext_vector_type(8)));
typedef _Float16 f16x4 __attribute__((ext_vector_type(4)));
typedef float floatx16 __attribute__((ext_vector_type(16)));

__device__ inline void atomicMaxFloatPos(float* a, float v) {
    atomicMax((int*)a, __float_as_int(v));   // valid: all values >= 0
}
__device__ inline void atomicMinFloatPos(float* a, float v) {
    atomicMin((int*)a, __float_as_int(v));
}

// async 16B global -> LDS (wave-uniform LDS base + lane*16)
__device__ inline void gl_lds16(const void* g, void* l) {
    __builtin_amdgcn_global_load_lds(
        (const __attribute__((address_space(1))) unsigned int*)g,
        (__attribute__((address_space(3))) unsigned int*)l, 16, 0, 0);
}

// Wave per row: convert x -> fp16 Xf (RNE), sq from the CONVERTED values
// (so the Gram diagonal cancels exactly), init ap/ang/anl.
__global__ __launch_bounds__(256) void prep_kernel(const float* __restrict__ x,
                                                   float* __restrict__ sq,
                                                   _Float16* __restrict__ Xf,
                                                   float* ap, float* ang, float* anl) {
    const int wave = threadIdx.x >> 6, lane = threadIdx.x & 63;
    const int row = blockIdx.x * 4 + wave;
    const float4 v = *(const float4*)(x + (size_t)row * D + lane * 4);
    f16x4 h;
    h[0] = (_Float16)v.x; h[1] = (_Float16)v.y;
    h[2] = (_Float16)v.z; h[3] = (_Float16)v.w;
    *(f16x4*)(Xf + (size_t)row * D + lane * 4) = h;
    const float c0 = (float)h[0], c1 = (float)h[1], c2 = (float)h[2], c3 = (float)h[3];
    float s = c0 * c0 + c1 * c1 + c2 * c2 + c3 * c3;
    #pragma unroll
    for (int off = 32; off; off >>= 1) s += __shfl_down(s, off);
    if (lane == 0) sq[row] = s;
    if (threadIdx.x < 4) {
        const int i = blockIdx.x * 4 + threadIdx.x;
        ap[i] = 0.0f; ang[i] = BIG; anl[i] = BIG;
    }
}

// One wave per 64x64 tile; NO barriers. Double-buffered DMA pipeline:
// issue stage s+1 (16 x global_load_lds of 16B), s_waitcnt vmcnt(16) so
// stage s has landed while s+1 stays in flight, compute stage s. Only the
// prologue pays full memory latency.
// LDS tile row = 128 B = 8 chunks of 16 B; logical chunk q of row r stored
// at phys q ^ (r&7) (conflict-free ds_read_b128). 2 buffers: 32 KiB total.
// Epilogue: phase A computes d, coalesced global stores + swizzled LDS f32
// tile; phase B: lane = row, serial reduce over 64 cols, 3 atomics.
__global__ __launch_bounds__(64) void dist_kernel(const _Float16* __restrict__ Xf,
                                                  const int* __restrict__ tgt,
                                                  const float* __restrict__ sq,
                                                  float* __restrict__ dist,
                                                  float* ap, float* ang, float* anl) {
    __shared__ _Float16 lds[16384];         // 32 KiB
    _Float16* A0 = lds;                     // stage buffers (8 KiB each)
    _Float16* B0 = lds + 4096;
    _Float16* A1 = lds + 8192;
    _Float16* B1 = lds + 12288;
    float*    ldsC = (float*)lds;           // epilogue 64x64 f32 (16 KiB)

    const int lane = threadIdx.x;
    const int row0 = blockIdx.y * 64;
    const int col0 = blockIdx.x * 64;

    // DMA source mapping: lane -> row-in-8-group (drow), phys chunk (lane&7);
    // fetch logical chunk q = (lane&7) ^ drow so frag reads are conflict-free.
    const int drow = lane >> 3;                    // 0..7
    const int q    = (lane & 7) ^ drow;            // logical chunk 0..7
    const _Float16* gA = Xf + (size_t)(row0 + drow) * D + q * 8;
    const _Float16* gB = Xf + (size_t)(col0 + drow) * D + q * 8;

    const int m0 = lane & 31;
    const int m1 = 32 + m0;

    #define ISSUE(k0, la, lb)                                             \
        {                                                                 \
            _Pragma("unroll")                                             \
            for (int d = 0; d < 8; ++d) {                                 \
                gl_lds16(gA + (size_t)d * 8 * D + (k0), (la) + d * 512);  \
                gl_lds16(gB + (size_t)d * 8 * D + (k0), (lb) + d * 512);  \
            }                                                             \
        }

    #define COMPUTE(la, lb)                                                            \
        {                                                                              \
            _Pragma("unroll")                                                          \
            for (int ks = 0; ks < 4; ++ks) {                                           \
                const int lq = ks * 2 + (lane >> 5);                                   \
                f16x8 a0 = *(const f16x8*)((la) + m0 * 64 + ((lq ^ (m0 & 7)) << 3));   \
                f16x8 a1 = *(const f16x8*)((la) + m1 * 64 + ((lq ^ (m1 & 7)) << 3));   \
                f16x8 b0 = *(const f16x8*)((lb) + m0 * 64 + ((lq ^ (m0 & 7)) << 3));   \
                f16x8 b1 = *(const f16x8*)((lb) + m1 * 64 + ((lq ^ (m1 & 7)) << 3));   \
                acc[0][0] = __builtin_amdgcn_mfma_f32_32x32x16_f16(a0, b0, acc[0][0], 0, 0, 0); \
                acc[0][1] = __builtin_amdgcn_mfma_f32_32x32x16_f16(a0, b1, acc[0][1], 0, 0, 0); \
                acc[1][0] = __builtin_amdgcn_mfma_f32_32x32x16_f16(a1, b0, acc[1][0], 0, 0, 0); \
                acc[1][1] = __builtin_amdgcn_mfma_f32_32x32x16_f16(a1, b1, acc[1][1], 0, 0, 0); \
            }                                                                          \
        }

    ISSUE(0, A0, B0);                       // stage 0 in flight ASAP

    floatx16 acc[2][2];
    #pragma unroll
    for (int mt = 0; mt < 2; ++mt)
        #pragma unroll
        for (int nt = 0; nt < 2; ++nt)
            #pragma unroll
            for (int r = 0; r < 16; ++r) acc[mt][nt][r] = 0.0f;

    ISSUE(64, A1, B1);                      // stage 1 in flight
    __asm__ volatile("s_waitcnt vmcnt(16)" ::: "memory");   // stage 0 landed
    COMPUTE(A0, B0);
    ISSUE(128, A0, B0);                     // stage 2 (buf0 reads retired)
    __asm__ volatile("s_waitcnt vmcnt(16)" ::: "memory");   // stage 1 landed
    COMPUTE(A1, B1);
    ISSUE(192, A1, B1);                     // stage 3
    __asm__ volatile("s_waitcnt vmcnt(16)" ::: "memory");   // stage 2 landed
    COMPUTE(A0, B0);
    __asm__ volatile("s_waitcnt vmcnt(0)" ::: "memory");    // stage 3 landed
    COMPUTE(A1, B1);

    // ---- Epilogue phase A: d = sqrt(sqi + sqj - 2*dot); coalesced global
    // stores + swizzled LDS f32 tile. C/D layout: col = lane&31,
    // row = (r&3) + 8*(r>>2) + 4*(lane>>5).
    const int gc0 = col0 + m0, gc1 = col0 + 32 + m0;
    const float sqc0 = sq[gc0], sqc1 = sq[gc1];
    const int rl_base = 4 * (lane >> 5);

    #pragma unroll
    for (int mt = 0; mt < 2; ++mt) {
        #pragma unroll
        for (int r = 0; r < 16; ++r) {
            const int row_l = mt * 32 + (r & 3) + 8 * (r >> 2) + rl_base;
            const int grow  = row0 + row_l;
            const float sqi = sq[grow];
            const float d0 = sqrtf(fmaxf(sqi + sqc0 - 2.0f * acc[mt][0][r], 0.0f));
            const float d1 = sqrtf(fmaxf(sqi + sqc1 - 2.0f * acc[mt][1][r], 0.0f));
            dist[(size_t)grow * N + gc0] = d0;
            dist[(size_t)grow * N + gc1] = d1;
            const int sw = row_l & 15;
            ldsC[row_l * 64 + (((m0 >> 2) ^ sw) << 2) + (m0 & 3)] = d0;
            ldsC[row_l * 64 + ((((m0 + 32) >> 2) ^ sw) << 2) + (m0 & 3)] = d1;
        }
    }
    __asm__ volatile("s_waitcnt lgkmcnt(0)" ::: "memory");

    // ---- Phase B: lane = row, serial reduce over 64 cols, 3 atomics.
    const int grow = row0 + lane;
    const int ti   = tgt[grow];
    float mx = 0.0f, mg = BIG, ml = BIG;
    #pragma unroll
    for (int j = 0; j < 16; ++j) {
        const int4  t4 = *(const int4*)&tgt[col0 + j * 4];    // uniform addr
        const float4 d4 = *(const float4*)&ldsC[lane * 64 + ((j ^ (lane & 15)) << 2)];
        if (t4.x == ti) mx = fmaxf(mx, d4.x); else if (t4.x > ti) mg = fminf(mg, d4.x); else ml = fminf(ml, d4.x);
        if (t4.y == ti) mx = fmaxf(mx, d4.y); else if (t4.y > ti) mg = fminf(mg, d4.y); else ml = fminf(ml, d4.y);
        if (t4.z == ti) mx = fmaxf(mx, d4.z); else if (t4.z > ti) mg = fminf(mg, d4.z); else ml = fminf(ml, d4.z);
        if (t4.w == ti) mx = fmaxf(mx, d4.w); else if (t4.w > ti) mg = fminf(mg, d4.w); else ml = fminf(ml, d4.w);
    }
    atomicMaxFloatPos(&ap[grow], mx);
    atomicMinFloatPos(&ang[grow], mg);
    atomicMinFloatPos(&anl[grow], ml);
    #undef ISSUE
    #undef COMPUTE
}

// One block: histogram (packed wave reduce), then loss/cnt, write outputs.
__global__ __launch_bounds__(1024) void finish_kernel(const float* __restrict__ ap,
                                                      const float* __restrict__ ang,
                                                      const float* __restrict__ anl,
                                                      const int* __restrict__ tgt,
                                                      float* __restrict__ out) {
    __shared__ int hist[4];
    __shared__ unsigned hsum[2][16];
    __shared__ float wsum[16];
    __shared__ int wcnt[16];
    const int tid = threadIdx.x, lane = tid & 63, wv = tid >> 6;

    const int4 t4 = *(const int4*)&tgt[tid * 4];
    int c[4] = {0, 0, 0, 0};
    c[t4.x & 3]++; c[t4.y & 3]++; c[t4.z & 3]++; c[t4.w & 3]++;
    unsigned p01 = (unsigned)c[0] | ((unsigned)c[1] << 16);
    unsigned p23 = (unsigned)c[2] | ((unsigned)c[3] << 16);
    #pragma unroll
    for (int off = 32; off; off >>= 1) {
        p01 += __shfl_down(p01, off);
        p23 += __shfl_down(p23, off);
    }
    if (lane == 0) { hsum[0][wv] = p01; hsum[1][wv] = p23; }
    __syncthreads();
    if (tid == 0) {
        unsigned a = 0, b = 0;
        for (int i = 0; i < 16; ++i) { a += hsum[0][i]; b += hsum[1][i]; }
        hist[0] = a & 0xFFFF; hist[1] = a >> 16;
        hist[2] = b & 0xFFFF; hist[3] = b >> 16;
    }
    __syncthreads();

    float term = 0.0f; int cc = 0;
    const int lab[4] = {t4.x & 3, t4.y & 3, t4.z & 3, t4.w & 3};
    #pragma unroll
    for (int j = 0; j < 4; ++j) {
        const int i = tid * 4 + j;
        term += fmaxf(ap[i] - fabsf(ang[i] - anl[i]) + MARGIN, 0.0f);
        cc += (hist[lab[j]] == 1) ? 1 : 0;
    }
    #pragma unroll
    for (int off = 32; off; off >>= 1) {
        term += __shfl_down(term, off);
        cc   += __shfl_down(cc, off);
    }
    if (lane == 0) { wsum[wv] = term; wcnt[wv] = cc; }
    __syncthreads();
    if (tid == 0) {
        float ls = 0.0f; int cs = 0;
        for (int i = 0; i < 16; ++i) { ls += wsum[i]; cs += wcnt[i]; }
        out[0] = ls * (1.0f / N);
        out[1 + (size_t)N * N] = (float)cs;
    }
}

extern "C" void kernel_launch(void* const* d_in, const int* in_sizes, int n_in,
                              void* d_out, int out_size, void* d_ws, size_t ws_size,
                              hipStream_t stream) {
    const float* x   = (const float*)d_in[0];
    const int*   tgt = (const int*)d_in[1];
    float* out = (float*)d_out;
    char*  ws  = (char*)d_ws;

    _Float16* Xf  = (_Float16*)ws;                    // 2 MiB, 16B-aligned
    float*    sq  = (float*)(ws + 2097152);
    float*    ap  = sq + 4096;
    float*    ang = sq + 8192;
    float*    anl = sq + 12288;

    prep_kernel<<<N / 4, 256, 0, stream>>>(x, sq, Xf, ap, ang, anl);
    dim3 grid(N / 64, N / 64);
    dist_kernel<<<grid, 64, 0, stream>>>(Xf, tgt, sq, out + 1, ap, ang, anl);
    finish_kernel<<<1, 1024, 0, stream>>>(ap, ang, anl, tgt, out);
}